// Round 11
// baseline (60.449 us; speedup 1.0000x reference)
//
#include <hip/hip_runtime.h>
#include <math.h>

// Problem: S=4096, B=16, H=1024
//   energies[b,s] = hidden[b,:] . (W @ enc[s,b,:] + b_attn)
//   out[b,0,s]    = softmax_s(energies[b,s])
// Reassociated: energies[b,s] = v[b,:] . enc[s,b,:] (+ const_b, cancels under
// softmax shift-invariance), v = hidden @ W.  b_attn never read.
//
// Refuted: coop-API fusion (R4 spills); spin-barrier fusion (R9, ~4us/bar);
// nontemporal (R2); B@64-VGPR-cap (R6); low-wave GEMV (R8); atomic-A (R10,
// +2.5us vs A1+A2). Best = R7 (56.7us).
// R11 = R7 with B's LDS eliminated: a wave's 4 pairs have FIXED b =
// (wi*4+j)&15 across tiles (tile stride 16384 = 0 mod 16), so the 4 needed
// v-rows live in 64 VGPRs loaded once -> no staging, no ds_read on the
// stream path, pure global_load+FMA inner loop.

#define SS 4096
#define BB 16
#define HH 1024
#define KC 16          // k-chunks for split-k GEMV
#define KLEN (HH / KC) // 64

#define BNB 512        // kernel B: blocks
#define BNT 512        // kernel B: threads per block (8 waves)
#define NGRP (SS * BB / 32)   // 2048 groups of 32 consecutive pairs
#define TILES (NGRP / BNB)    // 4 groups per block

typedef float f4 __attribute__((ext_vector_type(4)));

// ---- A1: partial[kc][b*HH+h] = sum_{k in chunk kc} hidden[b,k] * W[k,h] ----
// (R7 verbatim) 1024 blocks x 256 threads = 4096 waves; W coalesced over h.
__global__ void __launch_bounds__(256)
gemv_partial_kernel(const float* __restrict__ hidden,
                    const float* __restrict__ W,
                    float* __restrict__ partial) {
    int blk = blockIdx.x;          // 0..1023
    int kc  = blk >> 6;            // 16 chunks
    int rb  = blk & 63;            // b(16) x hchunk(4)
    int b   = rb >> 2;
    int h   = ((rb & 3) << 8) | threadIdx.x;
    const float* hrow = hidden + b * HH + kc * KLEN;
    const float* Wp   = W + (size_t)(kc * KLEN) * HH + h;
    float a0 = 0.f, a1 = 0.f, a2 = 0.f, a3 = 0.f;
    #pragma unroll 4
    for (int k = 0; k < KLEN; k += 4) {
        a0 += hrow[k + 0] * Wp[(k + 0) * HH];
        a1 += hrow[k + 1] * Wp[(k + 1) * HH];
        a2 += hrow[k + 2] * Wp[(k + 2) * HH];
        a3 += hrow[k + 3] * Wp[(k + 3) * HH];
    }
    partial[kc * (BB * HH) + b * HH + h] = (a0 + a1) + (a2 + a3);
}

// ---- A2: v[i] = sum_kc partial[kc][i]  (R7 verbatim) ----------------------
__global__ void __launch_bounds__(256)
gemv_reduce_kernel(const float* __restrict__ partial,
                   float* __restrict__ v) {
    int i = blockIdx.x * 256 + threadIdx.x;   // 0..16383
    float s = 0.f;
    #pragma unroll
    for (int kc = 0; kc < KC; ++kc) s += partial[kc * (BB * HH) + i];
    v[i] = s;
}

// ---- B: energies[b,s] = v[b,:] . enc[s,b,:]  (no-LDS, v in VGPRs) ---------
// 512 blocks x 512 threads. Wave wi's pairs p0+j (j=0..3) have b=(wi*4+j)&15
// for EVERY tile, so the wave loads its 4 v-rows (4 KB x 4) into 64 VGPRs
// once (from L2-hot v), then sweeps 4 tiles of 4 consecutive pairs: inner
// loop is pure coalesced global_load_dwordx4 + FMA -> no LDS anywhere.
// Butterfly-reduce, lane0 writes 4 scalars.
__global__ void __launch_bounds__(BNT, 4)
energies_kernel(const float* __restrict__ enc,
                const float* __restrict__ v,
                float* __restrict__ out) {
    int tid  = threadIdx.x;
    int lane = tid & 63;
    int wi   = tid >> 6;                    // wave in block, 0..7
    const f4* vg = (const f4*)v;
    f4 vv[4][4];                            // 4 rows x 16 floats/lane
    #pragma unroll
    for (int j = 0; j < 4; ++j) {
        int bj = (wi * 4 + j) & (BB - 1);
        #pragma unroll
        for (int i = 0; i < 4; ++i)
            vv[j][i] = vg[bj * 256 + i * 64 + lane];
    }

    #pragma unroll
    for (int t = 0; t < TILES; ++t) {
        int g  = t * BNB + blockIdx.x;      // group 0..2047
        int p0 = g * 32 + wi * 4;           // first of 4 consecutive pairs
        float acc[4];
        #pragma unroll
        for (int j = 0; j < 4; ++j) {
            const f4* e4 = (const f4*)(enc + (size_t)(p0 + j) * HH);
            f4 a0 = e4[0 * 64 + lane];
            f4 a1 = e4[1 * 64 + lane];
            f4 a2 = e4[2 * 64 + lane];
            f4 a3 = e4[3 * 64 + lane];
            f4 pr = a0 * vv[j][0] + a1 * vv[j][1] + a2 * vv[j][2] + a3 * vv[j][3];
            acc[j] = (pr.x + pr.y) + (pr.z + pr.w);
        }
        #pragma unroll
        for (int j = 0; j < 4; ++j) {
            #pragma unroll
            for (int off = 32; off; off >>= 1)
                acc[j] += __shfl_xor(acc[j], off, 64);
        }
        if (lane == 0) {
            #pragma unroll
            for (int j = 0; j < 4; ++j) {
                int p = p0 + j;
                out[(p & (BB - 1)) * SS + (p >> 4)] = acc[j];
            }
        }
    }
}

// ---- C: in-place softmax over s, one 256-thread block per b (unchanged) ---
__global__ void __launch_bounds__(256)
softmax_kernel(float* __restrict__ out) {
    int b = blockIdx.x;
    float* row = out + b * SS;
    int t = threadIdx.x;                 // 16 values per thread
    float vals[16];
    float m = -INFINITY;
    #pragma unroll
    for (int i = 0; i < 16; ++i) {
        vals[i] = row[t + i * 256];
        m = fmaxf(m, vals[i]);
    }
    #pragma unroll
    for (int off = 32; off; off >>= 1) m = fmaxf(m, __shfl_xor(m, off, 64));
    __shared__ float redm[4];
    __shared__ float reds[4];
    int wid = t >> 6;
    if ((t & 63) == 0) redm[wid] = m;
    __syncthreads();
    m = fmaxf(fmaxf(redm[0], redm[1]), fmaxf(redm[2], redm[3]));

    float sum = 0.f;
    #pragma unroll
    for (int i = 0; i < 16; ++i) {
        vals[i] = expf(vals[i] - m);
        sum += vals[i];
    }
    #pragma unroll
    for (int off = 32; off; off >>= 1) sum += __shfl_xor(sum, off, 64);
    if ((t & 63) == 0) reds[wid] = sum;
    __syncthreads();
    sum = reds[0] + reds[1] + reds[2] + reds[3];
    float inv = 1.0f / sum;
    #pragma unroll
    for (int i = 0; i < 16; ++i) row[t + i * 256] = vals[i] * inv;
}

extern "C" void kernel_launch(void* const* d_in, const int* in_sizes, int n_in,
                              void* d_out, int out_size, void* d_ws, size_t ws_size,
                              hipStream_t stream) {
    const float* hidden = (const float*)d_in[0];   // [1,B,H]
    const float* enc    = (const float*)d_in[1];   // [S,B,H]
    const float* W      = (const float*)d_in[2];   // [H,H]
    // d_in[3] = b_attn: cancels in softmax (and is zero in setup_inputs)
    float* out     = (float*)d_out;                // [B,1,S]
    float* v       = (float*)d_ws;                 // B*H floats    = 64 KB
    float* partial = v + BB * HH;                  // KC*B*H floats = 1 MB

    hipLaunchKernelGGL(gemv_partial_kernel, dim3(KC * 64), dim3(256), 0, stream,
                       hidden, W, partial);
    hipLaunchKernelGGL(gemv_reduce_kernel, dim3(BB * HH / 256), dim3(256), 0, stream,
                       partial, v);
    hipLaunchKernelGGL(energies_kernel, dim3(BNB), dim3(BNT), 0, stream,
                       enc, v, out);
    hipLaunchKernelGGL(softmax_kernel, dim3(BB), dim3(256), 0, stream, out);
}

// Round 12
// 56.478 us; speedup vs baseline: 1.0703x; 1.0703x over previous
//
#include <hip/hip_runtime.h>
#include <math.h>

// Problem: S=4096, B=16, H=1024
//   energies[b,s] = hidden[b,:] . (W @ enc[s,b,:] + b_attn)
//   out[b,0,s]    = softmax_s(energies[b,s])
// Reassociated: energies[b,s] = v[b,:] . enc[s,b,:] (+ const_b, cancels under
// softmax shift-invariance), v = hidden @ W.  b_attn never read.
//
// Refuted: coop-API fusion (R4 spills); spin-barrier fusion (R9 ~4us/bar);
// nontemporal (R2); B@64-VGPR-cap (R6); low-wave GEMV (R8); atomic-A (R10);
// reg-v B (R11). B pinned ~44us = ~93% of 6.29 TB/s read ceiling across 4
// structures (R5/R7/R9-P2/R11).
// R12 = R7 with A1+A2 fused into ONE dispatch that keeps A1's exact recipe:
// 256 blocks x 1024 threads = 4096 waves, 64-deep k-loops (R8 failed with
// 1024 waves x 256-deep), in-block LDS reduce replaces the 2 MB partial
// round-trip + A2's dispatch + edge.
//   A : fused GEMV (256 blk x 16 waves)               ~2.5-3 us
//   B : persistent contiguous stream, v in LDS (R7)   ~44 us (read wall)
//   C : per-b softmax in-place on d_out (R7)          ~2.5 us

#define SS 4096
#define BB 16
#define HH 1024

#define BNB 512        // kernel B: blocks (2 per CU, LDS-capped)
#define BNT 512        // kernel B: threads per block (8 waves)
#define NGRP (SS * BB / 32)   // 2048 groups of 32 consecutive pairs
#define TILES (NGRP / BNB)    // 4 groups per block

typedef float f4 __attribute__((ext_vector_type(4)));

// ---- A: v[b,h] = sum_k hidden[b,k] * W[k,h]  (ONE dispatch, A1's recipe) ---
// 256 blocks x 1024 threads = 4096 waves. Block -> (b = bid>>4, h-chunk of
// 64). Thread: h = hbase|(tid&63), kc = tid>>6 -> 16 k-chunks x 64-deep
// (A1's exact per-thread shape). Wave = 64 consecutive h -> W reads 256 B
// coalesced, hidden[b,k] wave-uniform. 16 partials per h meet in 4 KB LDS;
// threads 0..63 sum 16 each (conflict-free: consecutive lanes read
// consecutive red[kc*64+..]) and write v.
__global__ void __launch_bounds__(1024)
gemv_fused_kernel(const float* __restrict__ hidden,
                  const float* __restrict__ W,
                  float* __restrict__ v) {
    __shared__ float red[1024];
    int tid   = threadIdx.x;
    int b     = blockIdx.x >> 4;
    int hbase = (blockIdx.x & 15) << 6;
    int ho    = tid & 63;
    int kc    = tid >> 6;                    // 0..15
    int h     = hbase | ho;
    const float* hrow = hidden + b * HH + kc * 64;
    const float* Wp   = W + (size_t)(kc * 64) * HH + h;
    float a0 = 0.f, a1 = 0.f, a2 = 0.f, a3 = 0.f;
    #pragma unroll 4
    for (int k = 0; k < 64; k += 4) {
        a0 += hrow[k + 0] * Wp[(k + 0) * HH];
        a1 += hrow[k + 1] * Wp[(k + 1) * HH];
        a2 += hrow[k + 2] * Wp[(k + 2) * HH];
        a3 += hrow[k + 3] * Wp[(k + 3) * HH];
    }
    red[tid] = (a0 + a1) + (a2 + a3);
    __syncthreads();
    if (tid < 64) {
        float s = 0.f;
        #pragma unroll
        for (int k2 = 0; k2 < 16; ++k2) s += red[k2 * 64 + tid];
        v[b * HH + hbase + tid] = s;
    }
}

// ---- B: energies[b,s] = v[b,:] . enc[s,b,:]  (R7 verbatim — at the wall) --
// 512 blocks x 512 threads, 2 blocks/CU (LDS 64 KB/block). Each block stages
// the whole v (64 KB) into LDS once, then sweeps TILES=4 groups of 32
// CONSECUTIVE pairs p = s*16+b; wave i takes pairs p0=g*32+i*4..+3, i.e. one
// contiguous 16 KB span of enc per wave per tile. vv comes from LDS per pair
// (conflict-free consecutive-lane ds_read_b128). Butterfly-reduce, lane0
// writes 4 floats.
__global__ void __launch_bounds__(BNT, 4)
energies_kernel(const float* __restrict__ enc,
                const float* __restrict__ v,
                float* __restrict__ out) {
    __shared__ f4 vlds[BB * HH / 4];        // 4096 f4 = 64 KB
    int tid = threadIdx.x;
    const f4* vg = (const f4*)v;
    #pragma unroll
    for (int it = 0; it < (BB * HH / 4) / BNT; ++it)   // 8 iters
        vlds[it * BNT + tid] = vg[it * BNT + tid];
    __syncthreads();

    int lane = tid & 63;
    int wi   = tid >> 6;                    // wave in block, 0..7
    for (int t = 0; t < TILES; ++t) {
        int g  = t * BNB + blockIdx.x;      // group 0..2047
        int p0 = g * 32 + wi * 4;           // first of 4 consecutive pairs
        float acc[4];
        #pragma unroll
        for (int j = 0; j < 4; ++j) {
            int p = p0 + j;
            int b = p & (BB - 1);
            const f4* e4 = (const f4*)(enc + (size_t)p * HH);
            f4 a0 = e4[0 * 64 + lane];
            f4 a1 = e4[1 * 64 + lane];
            f4 a2 = e4[2 * 64 + lane];
            f4 a3 = e4[3 * 64 + lane];
            f4 w0 = vlds[b * 256 + 0 * 64 + lane];
            f4 w1 = vlds[b * 256 + 1 * 64 + lane];
            f4 w2 = vlds[b * 256 + 2 * 64 + lane];
            f4 w3 = vlds[b * 256 + 3 * 64 + lane];
            f4 pr = a0 * w0 + a1 * w1 + a2 * w2 + a3 * w3;
            acc[j] = (pr.x + pr.y) + (pr.z + pr.w);
        }
        #pragma unroll
        for (int j = 0; j < 4; ++j) {
            #pragma unroll
            for (int off = 32; off; off >>= 1)
                acc[j] += __shfl_xor(acc[j], off, 64);
        }
        if (lane == 0) {
            #pragma unroll
            for (int j = 0; j < 4; ++j) {
                int p = p0 + j;
                out[(p & (BB - 1)) * SS + (p >> 4)] = acc[j];
            }
        }
    }
}

// ---- C: in-place softmax over s, one 256-thread block per b (unchanged) ---
__global__ void __launch_bounds__(256)
softmax_kernel(float* __restrict__ out) {
    int b = blockIdx.x;
    float* row = out + b * SS;
    int t = threadIdx.x;                 // 16 values per thread
    float vals[16];
    float m = -INFINITY;
    #pragma unroll
    for (int i = 0; i < 16; ++i) {
        vals[i] = row[t + i * 256];
        m = fmaxf(m, vals[i]);
    }
    #pragma unroll
    for (int off = 32; off; off >>= 1) m = fmaxf(m, __shfl_xor(m, off, 64));
    __shared__ float redm[4];
    __shared__ float reds[4];
    int wid = t >> 6;
    if ((t & 63) == 0) redm[wid] = m;
    __syncthreads();
    m = fmaxf(fmaxf(redm[0], redm[1]), fmaxf(redm[2], redm[3]));

    float sum = 0.f;
    #pragma unroll
    for (int i = 0; i < 16; ++i) {
        vals[i] = expf(vals[i] - m);
        sum += vals[i];
    }
    #pragma unroll
    for (int off = 32; off; off >>= 1) sum += __shfl_xor(sum, off, 64);
    if ((t & 63) == 0) reds[wid] = sum;
    __syncthreads();
    sum = reds[0] + reds[1] + reds[2] + reds[3];
    float inv = 1.0f / sum;
    #pragma unroll
    for (int i = 0; i < 16; ++i) row[t + i * 256] = vals[i] * inv;
}

extern "C" void kernel_launch(void* const* d_in, const int* in_sizes, int n_in,
                              void* d_out, int out_size, void* d_ws, size_t ws_size,
                              hipStream_t stream) {
    const float* hidden = (const float*)d_in[0];   // [1,B,H]
    const float* enc    = (const float*)d_in[1];   // [S,B,H]
    const float* W      = (const float*)d_in[2];   // [H,H]
    // d_in[3] = b_attn: cancels in softmax (and is zero in setup_inputs)
    float* out = (float*)d_out;                    // [B,1,S]
    float* v   = (float*)d_ws;                     // B*H floats = 64 KB

    hipLaunchKernelGGL(gemv_fused_kernel, dim3(BB * 16), dim3(1024), 0, stream,
                       hidden, W, v);
    hipLaunchKernelGGL(energies_kernel, dim3(BNB), dim3(BNT), 0, stream,
                       enc, v, out);
    hipLaunchKernelGGL(softmax_kernel, dim3(BB), dim3(256), 0, stream, out);
}